// Round 1
// baseline (441.957 us; speedup 1.0000x reference)
//
#include <hip/hip_runtime.h>

#define Bn 32
#define Cn 64
#define Hn 64
#define Wn 64
#define On 128
#define HP 62
#define WP 62
#define CKn 576
#define Ln (HP*WP)          // 3844
#define Y_ELEMS (Bn*On*Ln)  // 15745024

typedef unsigned int uint32;
typedef unsigned short ushort16;
typedef __bf16 bf16x8 __attribute__((ext_vector_type(8)));
typedef float floatx4 __attribute__((ext_vector_type(4)));

static __device__ __forceinline__ uint32 bf16r(float f){
  uint32 u = __float_as_uint(f);
  return (u + 0x7FFFu + ((u >> 16) & 1u)) >> 16;
}

// ---------------- new-path ws layout (floats) ----------------
#define KSPLIT 4
#define GSZ   (On*CKn)            // 73728
#define NS1   0
#define NS2   128
#define NG    256                 // KSPLIT * GSZ floats = 294912
#define NWNB  (NG + KSPLIT*GSZ)   // 295168
#define NXB   (NWNB + 36864)      // 332032
#define NPB   (NXB + 4194304)     // 4526336
#define WS_NEED ((size_t)49800000)

__global__ __launch_bounds__(256) void k_norm(const float* __restrict__ w, ushort16* __restrict__ wnb,
                                              float* __restrict__ S1, float* __restrict__ S2,
                                              float* __restrict__ G, int ngbuf){
  int o = blockIdx.x; int t = threadIdx.x;
  for (int kq = 0; kq < ngbuf; kq++)
    for (int k = t; k < CKn; k += 256) G[(size_t)kq*GSZ + o*CKn + k] = 0.f;
  if (t == 0){ S1[o] = 0.f; S2[o] = 0.f; }
  float s = 0.f;
  for (int k = t; k < CKn; k += 256){ float v = w[o*CKn + k]; s += v*v; }
  #pragma unroll
  for (int off = 32; off; off >>= 1) s += __shfl_down(s, off);
  __shared__ float red[4]; __shared__ float sh_inv;
  if ((t & 63) == 0) red[t >> 6] = s;
  __syncthreads();
  if (t == 0){
    float tot = red[0] + red[1] + red[2] + red[3];
    float nrm = sqrtf(tot);
    sh_inv = (nrm == 0.f) ? 1.f : 1.f/nrm;
  }
  __syncthreads();
  float inv = sh_inv;
  for (int k = t; k < CKn; k += 256){
    float v = w[o*CKn + k] * inv;
    int c = k / 9;
    int q = k - c*9;
    wnb[o*CKn + q*64 + c] = (ushort16)bf16r(v);
  }
}

// x fp32 -> bf16, layout unchanged [b][c][h][w]
__global__ __launch_bounds__(256) void k_xb(const float* __restrict__ x, ushort16* __restrict__ xb){
  size_t idx = ((size_t)blockIdx.x*256 + threadIdx.x)*4;
  float4 v = *(const float4*)(x + idx);
  uint2 o;
  o.x = bf16r(v.x) | (bf16r(v.y) << 16);
  o.y = bf16r(v.z) | (bf16r(v.w) << 16);
  *(uint2*)(xb + idx) = o;
}

// MFMA implicit-GEMM conv (unchanged).
__global__ __launch_bounds__(256, 3) void k_convm(const float* __restrict__ x,
                                                  const ushort16* __restrict__ wnb,
                                                  const float* __restrict__ bias,
                                                  float* __restrict__ y){
  __shared__ ushort16 slab[4*64*68];
  __shared__ ushort16 Bl[2][128*36];
  int t = threadIdx.x;
  int lane = t & 63;
  int wv = t >> 6;
  int mtile = blockIdx.x;
  int b = blockIdx.y;
  int i0 = mtile*2;
  {
    int c0 = (t & 31)*2;
    int grp = t >> 5;
    int r = grp >> 1;
    int w0 = (grp & 1)*32;
    const float* p0 = x + (((size_t)b*Cn + c0)*Hn + (i0 + r))*Wn + w0;
    const float* p1 = p0 + (size_t)Hn*Wn;
    #pragma unroll
    for (int ch = 0; ch < 4; ch++){
      float4 A0 = *(const float4*)(p0 + ch*8);
      float4 A1 = *(const float4*)(p0 + ch*8 + 4);
      float4 B0 = *(const float4*)(p1 + ch*8);
      float4 B1 = *(const float4*)(p1 + ch*8 + 4);
      float v0[8] = {A0.x,A0.y,A0.z,A0.w,A1.x,A1.y,A1.z,A1.w};
      float v1[8] = {B0.x,B0.y,B0.z,B0.w,B1.x,B1.y,B1.z,B1.w};
      #pragma unroll
      for (int qq = 0; qq < 8; qq++){
        int wloc = w0 + ch*8 + qq;
        *(uint32*)&slab[(r*64 + wloc)*68 + c0] = (bf16r(v1[qq]) << 16) | bf16r(v0[qq]);
      }
    }
  }
  int ob = t >> 1;
  int kh16 = (t & 1)*16;
  const ushort16* wrow = wnb + (size_t)ob*CKn + kh16;
  {
    uint4 bA = *(const uint4*)(wrow);
    uint4 bB = *(const uint4*)(wrow + 8);
    ushort16* dst = &Bl[0][ob*36 + kh16];
    ((uint2*)dst)[0] = make_uint2(bA.x, bA.y);
    ((uint2*)dst)[1] = make_uint2(bA.z, bA.w);
    ((uint2*)dst)[2] = make_uint2(bB.x, bB.y);
    ((uint2*)dst)[3] = make_uint2(bB.z, bB.w);
  }
  int quad8 = (lane >> 4) << 3;
  int iT[2], jT[2];
  #pragma unroll
  for (int mt = 0; mt < 2; mt++){
    int m = wv*32 + mt*16 + (lane & 15);
    int pos = m < 124 ? m : 123;
    int hi = pos >= 62;
    iT[mt] = hi;
    jT[mt] = pos - (hi ? 62 : 0);
  }
  floatx4 acc[2][8];
  #pragma unroll
  for (int mt = 0; mt < 2; mt++)
    #pragma unroll
    for (int nt = 0; nt < 8; nt++)
      acc[mt][nt] = (floatx4){0.f, 0.f, 0.f, 0.f};
  union U8 { uint2 u[2]; bf16x8 v; };
  for (int s = 0; s < 18; s++){
    uint4 nA, nB;
    if (s < 17){
      nA = *(const uint4*)(wrow + (s+1)*32);
      nB = *(const uint4*)(wrow + (s+1)*32 + 8);
    }
    __syncthreads();
    int k0 = s*32 + quad8;
    int q = k0 >> 6;
    int c0 = k0 & 63;
    int kh = (q*86) >> 8;
    int kw = q - kh*3;
    bf16x8 af[2];
    #pragma unroll
    for (int mt = 0; mt < 2; mt++){
      const ushort16* ap = &slab[((iT[mt] + kh)*64 + jT[mt] + kw)*68 + c0];
      U8 ua;
      ua.u[0] = *(const uint2*)(ap);
      ua.u[1] = *(const uint2*)(ap + 4);
      af[mt] = ua.v;
    }
    const ushort16* bbase = &Bl[s & 1][(lane & 15)*36 + quad8];
    bf16x8 bf[8];
    #pragma unroll
    for (int nt = 0; nt < 8; nt++){
      const ushort16* bp = bbase + nt*576;
      U8 ub;
      ub.u[0] = *(const uint2*)(bp);
      ub.u[1] = *(const uint2*)(bp + 4);
      bf[nt] = ub.v;
    }
    #pragma unroll
    for (int mt = 0; mt < 2; mt++)
      #pragma unroll
      for (int nt = 0; nt < 8; nt++)
        acc[mt][nt] = __builtin_amdgcn_mfma_f32_16x16x32_bf16(af[mt], bf[nt], acc[mt][nt], 0, 0, 0);
    if (s < 17){
      ushort16* dst = &Bl[(s+1) & 1][ob*36 + kh16];
      ((uint2*)dst)[0] = make_uint2(nA.x, nA.y);
      ((uint2*)dst)[1] = make_uint2(nA.z, nA.w);
      ((uint2*)dst)[2] = make_uint2(nB.x, nB.y);
      ((uint2*)dst)[3] = make_uint2(nB.z, nB.w);
    }
  }
  float bv[8];
  #pragma unroll
  for (int nt = 0; nt < 8; nt++) bv[nt] = bias[nt*16 + (lane & 15)];
  #pragma unroll
  for (int mt = 0; mt < 2; mt++){
    #pragma unroll
    for (int reg = 0; reg < 4; reg++){
      int m = wv*32 + mt*16 + (lane >> 4)*4 + reg;
      if (m < 124){
        int hi = m >= 62;
        int ii = i0 + hi;
        int jj = m - (hi ? 62 : 0);
        float* yp = y + (((size_t)b*On)*HP + ii)*WP + jj;
        #pragma unroll
        for (int nt = 0; nt < 8; nt++){
          int o = nt*16 + (lane & 15);
          yp[(size_t)o*Ln] = acc[mt][nt][reg] + bv[nt];
        }
      }
    }
  }
}

// softmax v2 (unchanged)
__global__ __launch_bounds__(256) void k_softp(const float* __restrict__ y, ushort16* __restrict__ pb,
                                               float* __restrict__ S1, float* __restrict__ S2){
  __shared__ float mpart[2][256], dpart[2][256];
  __shared__ float s1loc[128], s2loc[128];
  int b = blockIdx.x;
  int s = blockIdx.y;          // 0..30
  int i0 = s*2;
  int t = threadIdx.x;
  int j = t & 63;
  int og = t >> 6;
  if (t < 128){ s1loc[t] = 0.f; s2loc[t] = 0.f; }
  int je = j < WP ? j : (WP-1);
  const float* yb = y + ((size_t)b*On)*Ln + (size_t)i0*WP + je;
  // pass 1
  float m0 = -3.0e38f, m1 = -3.0e38f, d0 = 0.f, d1 = 0.f;
  for (int oi = 0; oi < 32; oi++){
    int o = og*32 + oi;
    const float* yp = yb + (size_t)o*Ln;
    float v0 = yp[0];
    float v1 = yp[WP];
    float n0 = fmaxf(m0, v0);
    d0 = d0*__expf(m0 - n0) + __expf(v0 - n0);
    m0 = n0;
    float n1 = fmaxf(m1, v1);
    d1 = d1*__expf(m1 - n1) + __expf(v1 - n1);
    m1 = n1;
  }
  mpart[0][t] = m0; dpart[0][t] = d0;
  mpart[1][t] = m1; dpart[1][t] = d1;
  __syncthreads();
  float mc[2], ic[2];
  #pragma unroll
  for (int r = 0; r < 2; r++){
    float ma = mpart[r][j],      mb = mpart[r][64+j];
    float mcc = mpart[r][128+j], md = mpart[r][192+j];
    float mm = fmaxf(fmaxf(ma, mb), fmaxf(mcc, md));
    float dd = dpart[r][j]*__expf(ma-mm) + dpart[r][64+j]*__expf(mb-mm)
             + dpart[r][128+j]*__expf(mcc-mm) + dpart[r][192+j]*__expf(md-mm);
    mc[r] = mm; ic[r] = 1.f/dd;
  }
  // pass 2
  bool act = j < WP;
  for (int oi = 0; oi < 32; oi++){
    int o = og*32 + oi;
    const float* yp = yb + (size_t)o*Ln;
    float r0 = 0.f, r1 = 0.f;
    if (act){
      r0 = __expf(yp[0] - mc[0]) * ic[0];
      r1 = __expf(yp[WP] - mc[1]) * ic[1];
    }
    float p0 = r0*r0, p1 = r1*r1;
    ushort16* pp = pb + (((size_t)b*On + o)*HP + i0)*64 + j;
    pp[0]  = (ushort16)bf16r(p0);
    pp[64] = (ushort16)bf16r(p1);
    float s1v = r0 + r1, s2v = p0 + p1;
    #pragma unroll
    for (int off = 32; off; off >>= 1){ s1v += __shfl_down(s1v, off); s2v += __shfl_down(s2v, off); }
    if (j == 0){ s1loc[o] += s1v; s2loc[o] += s2v; }   // single writer per o per block
  }
  __syncthreads();
  if (t < 128){ atomicAdd(&S1[t], s1loc[t]); atomicAdd(&S2[t], s2loc[t]); }
}

// split-K MFMA delta, v2: 4-way spatial K-split (blockIdx.z) for occupancy.
// Baseline grid (16, Bn) = 512 blocks capped occupancy at 25% (measured 21.8%;
// MfmaUtil 6.5%, VALU 13%, HBM 12% => latency-bound, not enough waves).
// Each K-split has its own G buffer (same per-address atomic contention as before);
// k_finalm sums them.
__global__ __launch_bounds__(256) void k_deltam(const ushort16* __restrict__ xb,
                                                const ushort16* __restrict__ pb,
                                                float* __restrict__ G){
  __shared__ float Gl[32*144];
  int t = threadIdx.x;
  int lane = t & 63;
  int wv = t >> 6;
  int z = blockIdx.x;
  int b = blockIdx.y;
  int kq = blockIdx.z;
  int mg = z >> 2;
  int ntk = z & 3;
  for (int q = t; q < 32*144; q += 256) Gl[q] = 0.f;
  __syncthreads();
  int cl = lane & 15;
  int quad = lane >> 4;
  int quad8 = quad << 3;
  const ushort16* pA0 = pb + ((size_t)b*On + mg*32 + cl)*(HP*64);
  const ushort16* pA1 = pA0 + 16*(HP*64);
  const ushort16* xbase = xb + ((size_t)b*Cn + ntk*16 + cl)*(Hn*Wn);
  floatx4 acc[2][9];
  #pragma unroll
  for (int mt = 0; mt < 2; mt++)
    #pragma unroll
    for (int nt = 0; nt < 9; nt++)
      acc[mt][nt] = (floatx4){0.f, 0.f, 0.f, 0.f};
  union U16 { uint4 q; bf16x8 v; };
  // 124 k-slices balanced over 16 wave-slices (KSPLIT blocks x 4 waves), contiguous per block
  int wslice = kq*4 + wv;
  int ks0 = (wslice*124) >> 4;
  int ks1 = ((wslice+1)*124) >> 4;
  for (int ks = ks0; ks < ks1; ks++){
    int i = ks >> 1;
    int wb = ((ks & 1) << 5) + quad8;
    U16 a0, a1;
    a0.q = *(const uint4*)(pA0 + i*64 + wb);
    a1.q = *(const uint4*)(pA1 + i*64 + wb);
    uint4 d[3]; uint32 d4[3];
    #pragma unroll
    for (int kh = 0; kh < 3; kh++){
      const ushort16* xr = xbase + (i+kh)*Wn + wb;
      d[kh] = *(const uint4*)xr;
      d4[kh] = *(const uint32*)(xr + 8);
    }
    #pragma unroll
    for (int kh = 0; kh < 3; kh++){
      U16 f0, f1, f2;
      f0.q = d[kh];
      f1.q = make_uint4((d[kh].x>>16)|(d[kh].y<<16), (d[kh].y>>16)|(d[kh].z<<16),
                        (d[kh].z>>16)|(d[kh].w<<16), (d[kh].w>>16)|(d4[kh]<<16));
      f2.q = make_uint4(d[kh].y, d[kh].z, d[kh].w, d4[kh]);
      acc[0][kh*3+0] = __builtin_amdgcn_mfma_f32_16x16x32_bf16(a0.v, f0.v, acc[0][kh*3+0], 0, 0, 0);
      acc[1][kh*3+0] = __builtin_amdgcn_mfma_f32_16x16x32_bf16(a1.v, f0.v, acc[1][kh*3+0], 0, 0, 0);
      acc[0][kh*3+1] = __builtin_amdgcn_mfma_f32_16x16x32_bf16(a0.v, f1.v, acc[0][kh*3+1], 0, 0, 0);
      acc[1][kh*3+1] = __builtin_amdgcn_mfma_f32_16x16x32_bf16(a1.v, f1.v, acc[1][kh*3+1], 0, 0, 0);
      acc[0][kh*3+2] = __builtin_amdgcn_mfma_f32_16x16x32_bf16(a0.v, f2.v, acc[0][kh*3+2], 0, 0, 0);
      acc[1][kh*3+2] = __builtin_amdgcn_mfma_f32_16x16x32_bf16(a1.v, f2.v, acc[1][kh*3+2], 0, 0, 0);
    }
  }
  #pragma unroll
  for (int mt = 0; mt < 2; mt++)
    #pragma unroll
    for (int nt = 0; nt < 9; nt++)
      #pragma unroll
      for (int reg = 0; reg < 4; reg++){
        int ol = mt*16 + quad*4 + reg;
        int col = nt*16 + cl;
        atomicAdd(&Gl[ol*144 + col], acc[mt][nt][reg]);
      }
  __syncthreads();
  float* Gq = G + (size_t)kq*GSZ;
  for (int idx = t; idx < 32*144; idx += 256){
    int ol = idx / 144;
    int col = idx - ol*144;
    int q = col >> 4;
    int c = ntk*16 + (col & 15);
    atomicAdd(&Gq[(size_t)(mg*32 + ol)*CKn + q*64 + c], Gl[idx]);
  }
}

__global__ __launch_bounds__(576) void k_finalm(const float* __restrict__ w, const float* __restrict__ G,
                                                const float* __restrict__ S1, const float* __restrict__ S2,
                                                float* __restrict__ dw){
  int o = blockIdx.x; int k = threadIdx.x;
  int c = k / 9;
  int q = k - c*9;
  float s1 = S1[o]; if (s1 == 0.f) s1 = 1.f;
  float g = 0.f;
  #pragma unroll
  for (int kq = 0; kq < KSPLIT; kq++) g += G[(size_t)kq*GSZ + o*CKn + q*64 + c];
  dw[o*CKn + k] = (g - S2[o]*w[o*CKn + k]) / s1;
}

// ---------------- old fallback path ----------------
__global__ __launch_bounds__(256) void k_soft_old(const float* __restrict__ y, float* __restrict__ mbuf,
                                                  float* __restrict__ invdbuf, float* __restrict__ S1,
                                                  float* __restrict__ S2){
  __shared__ float s1loc[128], s2loc[128];
  int t = threadIdx.x;
  if (t < 128){ s1loc[t] = 0.f; s2loc[t] = 0.f; }
  __syncthreads();
  int b = blockIdx.x;
  int i = blockIdx.y*4 + (t >> 6);
  int j = t & 63;
  bool act = (i < 62) && (j < 62);
  const float* yp = y + (((size_t)b*On)*HP + (i < 62 ? i : 0))*WP + j;
  float mx = -3.0e38f;
  if (act){ for (int o = 0; o < On; o++) mx = fmaxf(mx, yp[(size_t)o*Ln]); }
  float den = 0.f;
  if (act){ for (int o = 0; o < On; o++) den += __expf(yp[(size_t)o*Ln] - mx); }
  float inv = act ? 1.f/den : 0.f;
  if (act){
    int pos = (b*HP + i)*WP + j;
    mbuf[pos] = mx; invdbuf[pos] = inv;
  }
  for (int o = 0; o < On; o++){
    float r = act ? __expf(yp[(size_t)o*Ln] - mx)*inv : 0.f;
    float s1v = r, s2v = r*r;
    #pragma unroll
    for (int off = 32; off; off >>= 1){ s1v += __shfl_down(s1v, off); s2v += __shfl_down(s2v, off); }
    if ((t & 63) == 0){ atomicAdd(&s1loc[o], s1v); atomicAdd(&s2loc[o], s2v); }
  }
  __syncthreads();
  if (t < 128){ atomicAdd(&S1[t], s1loc[t]); atomicAdd(&S2[t], s2loc[t]); }
}

__global__ __launch_bounds__(256) void k_delta_old(const float* __restrict__ x, const float* __restrict__ y,
                                                   const float* __restrict__ mbuf, const float* __restrict__ invdbuf,
                                                   float* __restrict__ G){
  __shared__ float planes[3][64][64];
  __shared__ float plds[16][64];
  int o0 = blockIdx.x * 16;
  int bs = blockIdx.y;
  int b = bs >> 2;
  int s = bs & 3;
  int i0 = s * 16;
  int nrows = (s == 3) ? 14 : 16;
  int t = threadIdx.x;
  int lane = t & 63;
  int w = t >> 6;
  int lc = t >> 2;
  int lw0 = (t & 3) << 4;
  const float* xb = x + (size_t)b*(Cn*Hn*Wn) + (size_t)lc*(Hn*Wn) + lw0;
  float acc[4][9];
  #pragma unroll
  for (int oi = 0; oi < 4; oi++)
    #pragma unroll
    for (int q = 0; q < 9; q++) acc[oi][q] = 0.f;
  #pragma unroll
  for (int pp = 0; pp < 2; pp++){
    int ih = i0 + pp;
    const float* src = xb + (size_t)ih*Wn;
    #pragma unroll
    for (int q = 0; q < 16; q++) planes[ih % 3][lw0 + q][lc] = src[q];
  }
  for (int ii = 0; ii < nrows; ii++){
    int i = i0 + ii;
    {
      int ih = i + 2;
      const float* src = xb + (size_t)ih*Wn;
      #pragma unroll
      for (int q = 0; q < 16; q++) planes[ih % 3][lw0 + q][lc] = src[q];
    }
    int R = b*HP + i;
    #pragma unroll
    for (int oi = 0; oi < 4; oi++){
      int o = o0 + w*4 + oi;
      float p = 0.f;
      if (lane < WP){
        int pos = R*WP + lane;
        float yv = y[(((size_t)b*On + o)*HP + i)*WP + lane];
        float r = __expf(yv - mbuf[pos]) * invdbuf[pos];
        p = r*r;
      }
      plds[w*4 + oi][lane] = p;
    }
    __syncthreads();
    int c = lane;
    int s0 = i % 3, s1 = (i+1) % 3, s2g = (i+2) % 3;
    #pragma unroll 1
    for (int jj0 = 0; jj0 < 56; jj0 += 8){
      float xv[3][12];
      #pragma unroll
      for (int q = 0; q < 12; q++){
        xv[0][q] = planes[s0][jj0+q][c];
        xv[1][q] = planes[s1][jj0+q][c];
        xv[2][q] = planes[s2g][jj0+q][c];
      }
      #pragma unroll
      for (int oi = 0; oi < 4; oi++){
        float4 pa = *(const float4*)&plds[w*4+oi][jj0];
        float4 pbq = *(const float4*)&plds[w*4+oi][jj0+4];
        float pv[8] = {pa.x,pa.y,pa.z,pa.w,pbq.x,pbq.y,pbq.z,pbq.w};
        #pragma unroll
        for (int kh = 0; kh < 3; kh++)
          #pragma unroll
          for (int kw = 0; kw < 3; kw++)
            #pragma unroll
            for (int dj = 0; dj < 8; dj++)
              acc[oi][kh*3+kw] += pv[dj]*xv[kh][dj+kw];
      }
    }
    {
      float xv[3][12];
      #pragma unroll
      for (int q = 0; q < 12; q++){
        bool ok = (56 + q) < 64;
        xv[0][q] = ok ? planes[s0][56+q][c] : 0.f;
        xv[1][q] = ok ? planes[s1][56+q][c] : 0.f;
        xv[2][q] = ok ? planes[s2g][56+q][c] : 0.f;
      }
      #pragma unroll
      for (int oi = 0; oi < 4; oi++){
        float4 pa = *(const float4*)&plds[w*4+oi][56];
        float4 pbq = *(const float4*)&plds[w*4+oi][60];
        float pv[8] = {pa.x,pa.y,pa.z,pa.w,pbq.x,pbq.y,pbq.z,pbq.w};
        #pragma unroll
        for (int kh = 0; kh < 3; kh++)
          #pragma unroll
          for (int kw = 0; kw < 3; kw++)
            #pragma unroll
            for (int dj = 0; dj < 8; dj++)
              acc[oi][kh*3+kw] += pv[dj]*xv[kh][dj+kw];
      }
    }
    __syncthreads();
  }
  #pragma unroll
  for (int oi = 0; oi < 4; oi++){
    float* Gr = G + (size_t)(o0 + w*4 + oi)*CKn + lane*9;
    #pragma unroll
    for (int q = 0; q < 9; q++) atomicAdd(&Gr[q], acc[oi][q]);
  }
}

__global__ __launch_bounds__(576) void k_final_old(const float* __restrict__ w, const float* __restrict__ G,
                                                   const float* __restrict__ S1, const float* __restrict__ S2,
                                                   float* __restrict__ dw){
  int o = blockIdx.x; int k = threadIdx.x;
  float s1 = S1[o]; if (s1 == 0.f) s1 = 1.f;
  dw[o*CKn + k] = (G[o*CKn + k] - S2[o]*w[o*CKn + k]) / s1;
}

extern "C" void kernel_launch(void* const* d_in, const int* in_sizes, int n_in,
                              void* d_out, int out_size, void* d_ws, size_t ws_size,
                              hipStream_t stream){
  const float* x    = (const float*)d_in[0];
  const float* w    = (const float*)d_in[1];
  const float* bias = (const float*)d_in[2];
  float* y  = (float*)d_out;
  float* dw = (float*)d_out + Y_ELEMS;
  float* ws = (float*)d_ws;

  if (ws_size >= WS_NEED){
    float* S1 = ws + NS1;
    float* S2 = ws + NS2;
    float* G  = ws + NG;
    ushort16* wnb = (ushort16*)(ws + NWNB);
    ushort16* xb  = (ushort16*)(ws + NXB);
    ushort16* pb  = (ushort16*)(ws + NPB);
    k_norm  <<<dim3(On),      dim3(256), 0, stream>>>(w, wnb, S1, S2, G, KSPLIT);
    k_xb    <<<dim3(8192),    dim3(256), 0, stream>>>(x, xb);
    k_convm <<<dim3(31, Bn),  dim3(256), 0, stream>>>(x, wnb, bias, y);
    k_softp <<<dim3(Bn, 31),  dim3(256), 0, stream>>>(y, pb, S1, S2);
    k_deltam<<<dim3(16, Bn, KSPLIT), dim3(256), 0, stream>>>(xb, pb, G);
    k_finalm<<<dim3(On),      dim3(CKn), 0, stream>>>(w, G, S1, S2, dw);
  } else {
    float* S1   = ws + 73728;
    float* S2   = ws + 73856;
    float* G    = ws + 73984;
    float* mbuf = ws + 147712;
    float* invd = ws + 270720;
    ushort16* wnb = (ushort16*)(ws + 393728);
    k_norm     <<<dim3(On),      dim3(256), 0, stream>>>(w, wnb, S1, S2, G, 1);
    k_convm    <<<dim3(31, Bn),  dim3(256), 0, stream>>>(x, wnb, bias, y);
    k_soft_old <<<dim3(Bn, 16),  dim3(256), 0, stream>>>(y, mbuf, invd, S1, S2);
    k_delta_old<<<dim3(8, Bn*4), dim3(256), 0, stream>>>(x, y, mbuf, invd, G);
    k_final_old<<<dim3(On),      dim3(CKn), 0, stream>>>(w, G, S1, S2, dw);
  }
}

// Round 2
// 332.178 us; speedup vs baseline: 1.3305x; 1.3305x over previous
//
#include <hip/hip_runtime.h>

#define Bn 32
#define Cn 64
#define Hn 64
#define Wn 64
#define On 128
#define HP 62
#define WP 62
#define CKn 576
#define Ln (HP*WP)          // 3844
#define Y_ELEMS (Bn*On*Ln)  // 15745024

typedef unsigned int uint32;
typedef unsigned short ushort16;
typedef __bf16 bf16x8 __attribute__((ext_vector_type(8)));
typedef float floatx4 __attribute__((ext_vector_type(4)));

static __device__ __forceinline__ uint32 bf16r(float f){
  uint32 u = __float_as_uint(f);
  return (u + 0x7FFFu + ((u >> 16) & 1u)) >> 16;
}

// ---------------- new-path ws layout (floats) ----------------
// G striped into KSB slices by (b&3): same total atomics as round 0 (2.36M)
// but 8-way per-address contention instead of 32-way.
#define KSB   4
#define GSZ   (On*CKn)            // 73728
#define NS1   0
#define NS2   128
#define NG    256                 // KSB * GSZ floats = 294912
#define NWNB  (NG + KSB*GSZ)      // 295168
#define NXB   (NWNB + 36864)      // 332032
#define NPB   (NXB + 4194304)     // 4526336  (proven-safe layout from round 1)
#define WS_NEED ((size_t)49800000)

__global__ __launch_bounds__(256) void k_norm(const float* __restrict__ w, ushort16* __restrict__ wnb,
                                              float* __restrict__ S1, float* __restrict__ S2,
                                              float* __restrict__ G, int ngbuf){
  int o = blockIdx.x; int t = threadIdx.x;
  for (int kq = 0; kq < ngbuf; kq++)
    for (int k = t; k < CKn; k += 256) G[(size_t)kq*GSZ + o*CKn + k] = 0.f;
  if (t == 0){ S1[o] = 0.f; S2[o] = 0.f; }
  float s = 0.f;
  for (int k = t; k < CKn; k += 256){ float v = w[o*CKn + k]; s += v*v; }
  #pragma unroll
  for (int off = 32; off; off >>= 1) s += __shfl_down(s, off);
  __shared__ float red[4]; __shared__ float sh_inv;
  if ((t & 63) == 0) red[t >> 6] = s;
  __syncthreads();
  if (t == 0){
    float tot = red[0] + red[1] + red[2] + red[3];
    float nrm = sqrtf(tot);
    sh_inv = (nrm == 0.f) ? 1.f : 1.f/nrm;
  }
  __syncthreads();
  float inv = sh_inv;
  for (int k = t; k < CKn; k += 256){
    float v = w[o*CKn + k] * inv;
    int c = k / 9;
    int q = k - c*9;
    wnb[o*CKn + q*64 + c] = (ushort16)bf16r(v);
  }
}

// x fp32 -> bf16, layout unchanged [b][c][h][w]
__global__ __launch_bounds__(256) void k_xb(const float* __restrict__ x, ushort16* __restrict__ xb){
  size_t idx = ((size_t)blockIdx.x*256 + threadIdx.x)*4;
  float4 v = *(const float4*)(x + idx);
  uint2 o;
  o.x = bf16r(v.x) | (bf16r(v.y) << 16);
  o.y = bf16r(v.z) | (bf16r(v.w) << 16);
  *(uint2*)(xb + idx) = o;
}

// MFMA implicit-GEMM conv (unchanged).
__global__ __launch_bounds__(256, 3) void k_convm(const float* __restrict__ x,
                                                  const ushort16* __restrict__ wnb,
                                                  const float* __restrict__ bias,
                                                  float* __restrict__ y){
  __shared__ ushort16 slab[4*64*68];
  __shared__ ushort16 Bl[2][128*36];
  int t = threadIdx.x;
  int lane = t & 63;
  int wv = t >> 6;
  int mtile = blockIdx.x;
  int b = blockIdx.y;
  int i0 = mtile*2;
  {
    int c0 = (t & 31)*2;
    int grp = t >> 5;
    int r = grp >> 1;
    int w0 = (grp & 1)*32;
    const float* p0 = x + (((size_t)b*Cn + c0)*Hn + (i0 + r))*Wn + w0;
    const float* p1 = p0 + (size_t)Hn*Wn;
    #pragma unroll
    for (int ch = 0; ch < 4; ch++){
      float4 A0 = *(const float4*)(p0 + ch*8);
      float4 A1 = *(const float4*)(p0 + ch*8 + 4);
      float4 B0 = *(const float4*)(p1 + ch*8);
      float4 B1 = *(const float4*)(p1 + ch*8 + 4);
      float v0[8] = {A0.x,A0.y,A0.z,A0.w,A1.x,A1.y,A1.z,A1.w};
      float v1[8] = {B0.x,B0.y,B0.z,B0.w,B1.x,B1.y,B1.z,B1.w};
      #pragma unroll
      for (int qq = 0; qq < 8; qq++){
        int wloc = w0 + ch*8 + qq;
        *(uint32*)&slab[(r*64 + wloc)*68 + c0] = (bf16r(v1[qq]) << 16) | bf16r(v0[qq]);
      }
    }
  }
  int ob = t >> 1;
  int kh16 = (t & 1)*16;
  const ushort16* wrow = wnb + (size_t)ob*CKn + kh16;
  {
    uint4 bA = *(const uint4*)(wrow);
    uint4 bB = *(const uint4*)(wrow + 8);
    ushort16* dst = &Bl[0][ob*36 + kh16];
    ((uint2*)dst)[0] = make_uint2(bA.x, bA.y);
    ((uint2*)dst)[1] = make_uint2(bA.z, bA.w);
    ((uint2*)dst)[2] = make_uint2(bB.x, bB.y);
    ((uint2*)dst)[3] = make_uint2(bB.z, bB.w);
  }
  int quad8 = (lane >> 4) << 3;
  int iT[2], jT[2];
  #pragma unroll
  for (int mt = 0; mt < 2; mt++){
    int m = wv*32 + mt*16 + (lane & 15);
    int pos = m < 124 ? m : 123;
    int hi = pos >= 62;
    iT[mt] = hi;
    jT[mt] = pos - (hi ? 62 : 0);
  }
  floatx4 acc[2][8];
  #pragma unroll
  for (int mt = 0; mt < 2; mt++)
    #pragma unroll
    for (int nt = 0; nt < 8; nt++)
      acc[mt][nt] = (floatx4){0.f, 0.f, 0.f, 0.f};
  union U8 { uint2 u[2]; bf16x8 v; };
  for (int s = 0; s < 18; s++){
    uint4 nA, nB;
    if (s < 17){
      nA = *(const uint4*)(wrow + (s+1)*32);
      nB = *(const uint4*)(wrow + (s+1)*32 + 8);
    }
    __syncthreads();
    int k0 = s*32 + quad8;
    int q = k0 >> 6;
    int c0 = k0 & 63;
    int kh = (q*86) >> 8;
    int kw = q - kh*3;
    bf16x8 af[2];
    #pragma unroll
    for (int mt = 0; mt < 2; mt++){
      const ushort16* ap = &slab[((iT[mt] + kh)*64 + jT[mt] + kw)*68 + c0];
      U8 ua;
      ua.u[0] = *(const uint2*)(ap);
      ua.u[1] = *(const uint2*)(ap + 4);
      af[mt] = ua.v;
    }
    const ushort16* bbase = &Bl[s & 1][(lane & 15)*36 + quad8];
    bf16x8 bf[8];
    #pragma unroll
    for (int nt = 0; nt < 8; nt++){
      const ushort16* bp = bbase + nt*576;
      U8 ub;
      ub.u[0] = *(const uint2*)(bp);
      ub.u[1] = *(const uint2*)(bp + 4);
      bf[nt] = ub.v;
    }
    #pragma unroll
    for (int mt = 0; mt < 2; mt++)
      #pragma unroll
      for (int nt = 0; nt < 8; nt++)
        acc[mt][nt] = __builtin_amdgcn_mfma_f32_16x16x32_bf16(af[mt], bf[nt], acc[mt][nt], 0, 0, 0);
    if (s < 17){
      ushort16* dst = &Bl[(s+1) & 1][ob*36 + kh16];
      ((uint2*)dst)[0] = make_uint2(nA.x, nA.y);
      ((uint2*)dst)[1] = make_uint2(nA.z, nA.w);
      ((uint2*)dst)[2] = make_uint2(nB.x, nB.y);
      ((uint2*)dst)[3] = make_uint2(nB.z, nB.w);
    }
  }
  float bv[8];
  #pragma unroll
  for (int nt = 0; nt < 8; nt++) bv[nt] = bias[nt*16 + (lane & 15)];
  #pragma unroll
  for (int mt = 0; mt < 2; mt++){
    #pragma unroll
    for (int reg = 0; reg < 4; reg++){
      int m = wv*32 + mt*16 + (lane >> 4)*4 + reg;
      if (m < 124){
        int hi = m >= 62;
        int ii = i0 + hi;
        int jj = m - (hi ? 62 : 0);
        float* yp = y + (((size_t)b*On)*HP + ii)*WP + jj;
        #pragma unroll
        for (int nt = 0; nt < 8; nt++){
          int o = nt*16 + (lane & 15);
          yp[(size_t)o*Ln] = acc[mt][nt][reg] + bv[nt];
        }
      }
    }
  }
}

// softmax v2 (unchanged)
__global__ __launch_bounds__(256) void k_softp(const float* __restrict__ y, ushort16* __restrict__ pb,
                                               float* __restrict__ S1, float* __restrict__ S2){
  __shared__ float mpart[2][256], dpart[2][256];
  __shared__ float s1loc[128], s2loc[128];
  int b = blockIdx.x;
  int s = blockIdx.y;          // 0..30
  int i0 = s*2;
  int t = threadIdx.x;
  int j = t & 63;
  int og = t >> 6;
  if (t < 128){ s1loc[t] = 0.f; s2loc[t] = 0.f; }
  int je = j < WP ? j : (WP-1);
  const float* yb = y + ((size_t)b*On)*Ln + (size_t)i0*WP + je;
  // pass 1
  float m0 = -3.0e38f, m1 = -3.0e38f, d0 = 0.f, d1 = 0.f;
  for (int oi = 0; oi < 32; oi++){
    int o = og*32 + oi;
    const float* yp = yb + (size_t)o*Ln;
    float v0 = yp[0];
    float v1 = yp[WP];
    float n0 = fmaxf(m0, v0);
    d0 = d0*__expf(m0 - n0) + __expf(v0 - n0);
    m0 = n0;
    float n1 = fmaxf(m1, v1);
    d1 = d1*__expf(m1 - n1) + __expf(v1 - n1);
    m1 = n1;
  }
  mpart[0][t] = m0; dpart[0][t] = d0;
  mpart[1][t] = m1; dpart[1][t] = d1;
  __syncthreads();
  float mc[2], ic[2];
  #pragma unroll
  for (int r = 0; r < 2; r++){
    float ma = mpart[r][j],      mb = mpart[r][64+j];
    float mcc = mpart[r][128+j], md = mpart[r][192+j];
    float mm = fmaxf(fmaxf(ma, mb), fmaxf(mcc, md));
    float dd = dpart[r][j]*__expf(ma-mm) + dpart[r][64+j]*__expf(mb-mm)
             + dpart[r][128+j]*__expf(mcc-mm) + dpart[r][192+j]*__expf(md-mm);
    mc[r] = mm; ic[r] = 1.f/dd;
  }
  // pass 2
  bool act = j < WP;
  for (int oi = 0; oi < 32; oi++){
    int o = og*32 + oi;
    const float* yp = yb + (size_t)o*Ln;
    float r0 = 0.f, r1 = 0.f;
    if (act){
      r0 = __expf(yp[0] - mc[0]) * ic[0];
      r1 = __expf(yp[WP] - mc[1]) * ic[1];
    }
    float p0 = r0*r0, p1 = r1*r1;
    ushort16* pp = pb + (((size_t)b*On + o)*HP + i0)*64 + j;
    pp[0]  = (ushort16)bf16r(p0);
    pp[64] = (ushort16)bf16r(p1);
    float s1v = r0 + r1, s2v = p0 + p1;
    #pragma unroll
    for (int off = 32; off; off >>= 1){ s1v += __shfl_down(s1v, off); s2v += __shfl_down(s2v, off); }
    if (j == 0){ s1loc[o] += s1v; s2loc[o] += s2v; }   // single writer per o per block
  }
  __syncthreads();
  if (t < 128){ atomicAdd(&S1[t], s1loc[t]); atomicAdd(&S2[t], s2loc[t]); }
}

// MFMA delta v3: 16-o tiles. acc[9] = 36 AGPR (vs 72) -> reg cap 5 waves/SIMD;
// grid (32 z, 32 b) = 1024 blocks = 4 blocks/CU = 16 waves/CU (50% occupancy,
// one clean round, no grid tail). Total global atomics = 1024*2304 = 2.36M
// (round-0 level; round 1's 9.4M atomic storm was the regression). G striped
// by (b&3) into 4 slices -> 8-way per-address contention instead of 32-way.
__global__ __launch_bounds__(256) void k_deltam(const ushort16* __restrict__ xb,
                                                const ushort16* __restrict__ pb,
                                                float* __restrict__ G){
  __shared__ float Gl[16*144];
  int t = threadIdx.x;
  int lane = t & 63;
  int wv = t >> 6;
  int z = blockIdx.x;       // 0..31: mg = z>>2 (0..7), ntk = z&3
  int b = blockIdx.y;
  int mg = z >> 2;
  int ntk = z & 3;
  for (int q = t; q < 16*144; q += 256) Gl[q] = 0.f;
  __syncthreads();
  int cl = lane & 15;
  int quad = lane >> 4;
  int quad8 = quad << 3;
  const ushort16* pA = pb + ((size_t)b*On + mg*16 + cl)*(HP*64);
  const ushort16* xbase = xb + ((size_t)b*Cn + ntk*16 + cl)*(Hn*Wn);
  floatx4 acc[9];
  #pragma unroll
  for (int nt = 0; nt < 9; nt++) acc[nt] = (floatx4){0.f, 0.f, 0.f, 0.f};
  union U16 { uint4 q; bf16x8 v; };
  // 124 k-slices, 31 contiguous per wave
  for (int s = 0; s < 31; s++){
    int ks = wv*31 + s;
    int i = ks >> 1;
    int wb = ((ks & 1) << 5) + quad8;
    U16 a;
    a.q = *(const uint4*)(pA + i*64 + wb);
    uint4 d[3]; uint32 d4[3];
    #pragma unroll
    for (int kh = 0; kh < 3; kh++){
      const ushort16* xr = xbase + (i+kh)*Wn + wb;
      d[kh] = *(const uint4*)xr;
      d4[kh] = *(const uint32*)(xr + 8);
    }
    #pragma unroll
    for (int kh = 0; kh < 3; kh++){
      U16 f0, f1, f2;
      f0.q = d[kh];
      f1.q = make_uint4((d[kh].x>>16)|(d[kh].y<<16), (d[kh].y>>16)|(d[kh].z<<16),
                        (d[kh].z>>16)|(d[kh].w<<16), (d[kh].w>>16)|(d4[kh]<<16));
      f2.q = make_uint4(d[kh].y, d[kh].z, d[kh].w, d4[kh]);
      acc[kh*3+0] = __builtin_amdgcn_mfma_f32_16x16x32_bf16(a.v, f0.v, acc[kh*3+0], 0, 0, 0);
      acc[kh*3+1] = __builtin_amdgcn_mfma_f32_16x16x32_bf16(a.v, f1.v, acc[kh*3+1], 0, 0, 0);
      acc[kh*3+2] = __builtin_amdgcn_mfma_f32_16x16x32_bf16(a.v, f2.v, acc[kh*3+2], 0, 0, 0);
    }
  }
  // cross-wave reduce in LDS (4-way atomic), then one global atomic per element
  #pragma unroll
  for (int nt = 0; nt < 9; nt++)
    #pragma unroll
    for (int reg = 0; reg < 4; reg++)
      atomicAdd(&Gl[(quad*4 + reg)*144 + nt*16 + cl], acc[nt][reg]);
  __syncthreads();
  float* Gq = G + (size_t)(b & 3)*GSZ;
  for (int idx = t; idx < 16*144; idx += 256){
    int ol = idx / 144;
    int col = idx - ol*144;
    int q = col >> 4;
    int c = ntk*16 + (col & 15);
    atomicAdd(&Gq[(size_t)(mg*16 + ol)*CKn + q*64 + c], Gl[idx]);
  }
}

__global__ __launch_bounds__(576) void k_finalm(const float* __restrict__ w, const float* __restrict__ G,
                                                const float* __restrict__ S1, const float* __restrict__ S2,
                                                float* __restrict__ dw){
  int o = blockIdx.x; int k = threadIdx.x;
  int c = k / 9;
  int q = k - c*9;
  float s1 = S1[o]; if (s1 == 0.f) s1 = 1.f;
  float g = 0.f;
  #pragma unroll
  for (int kq = 0; kq < KSB; kq++) g += G[(size_t)kq*GSZ + o*CKn + q*64 + c];
  dw[o*CKn + k] = (g - S2[o]*w[o*CKn + k]) / s1;
}

// ---------------- old fallback path ----------------
__global__ __launch_bounds__(256) void k_soft_old(const float* __restrict__ y, float* __restrict__ mbuf,
                                                  float* __restrict__ invdbuf, float* __restrict__ S1,
                                                  float* __restrict__ S2){
  __shared__ float s1loc[128], s2loc[128];
  int t = threadIdx.x;
  if (t < 128){ s1loc[t] = 0.f; s2loc[t] = 0.f; }
  __syncthreads();
  int b = blockIdx.x;
  int i = blockIdx.y*4 + (t >> 6);
  int j = t & 63;
  bool act = (i < 62) && (j < 62);
  const float* yp = y + (((size_t)b*On)*HP + (i < 62 ? i : 0))*WP + j;
  float mx = -3.0e38f;
  if (act){ for (int o = 0; o < On; o++) mx = fmaxf(mx, yp[(size_t)o*Ln]); }
  float den = 0.f;
  if (act){ for (int o = 0; o < On; o++) den += __expf(yp[(size_t)o*Ln] - mx); }
  float inv = act ? 1.f/den : 0.f;
  if (act){
    int pos = (b*HP + i)*WP + j;
    mbuf[pos] = mx; invdbuf[pos] = inv;
  }
  for (int o = 0; o < On; o++){
    float r = act ? __expf(yp[(size_t)o*Ln] - mx)*inv : 0.f;
    float s1v = r, s2v = r*r;
    #pragma unroll
    for (int off = 32; off; off >>= 1){ s1v += __shfl_down(s1v, off); s2v += __shfl_down(s2v, off); }
    if ((t & 63) == 0){ atomicAdd(&s1loc[o], s1v); atomicAdd(&s2loc[o], s2v); }
  }
  __syncthreads();
  if (t < 128){ atomicAdd(&S1[t], s1loc[t]); atomicAdd(&S2[t], s2loc[t]); }
}

__global__ __launch_bounds__(256) void k_delta_old(const float* __restrict__ x, const float* __restrict__ y,
                                                   const float* __restrict__ mbuf, const float* __restrict__ invdbuf,
                                                   float* __restrict__ G){
  __shared__ float planes[3][64][64];
  __shared__ float plds[16][64];
  int o0 = blockIdx.x * 16;
  int bs = blockIdx.y;
  int b = bs >> 2;
  int s = bs & 3;
  int i0 = s * 16;
  int nrows = (s == 3) ? 14 : 16;
  int t = threadIdx.x;
  int lane = t & 63;
  int w = t >> 6;
  int lc = t >> 2;
  int lw0 = (t & 3) << 4;
  const float* xb = x + (size_t)b*(Cn*Hn*Wn) + (size_t)lc*(Hn*Wn) + lw0;
  float acc[4][9];
  #pragma unroll
  for (int oi = 0; oi < 4; oi++)
    #pragma unroll
    for (int q = 0; q < 9; q++) acc[oi][q] = 0.f;
  #pragma unroll
  for (int pp = 0; pp < 2; pp++){
    int ih = i0 + pp;
    const float* src = xb + (size_t)ih*Wn;
    #pragma unroll
    for (int q = 0; q < 16; q++) planes[ih % 3][lw0 + q][lc] = src[q];
  }
  for (int ii = 0; ii < nrows; ii++){
    int i = i0 + ii;
    {
      int ih = i + 2;
      const float* src = xb + (size_t)ih*Wn;
      #pragma unroll
      for (int q = 0; q < 16; q++) planes[ih % 3][lw0 + q][lc] = src[q];
    }
    int R = b*HP + i;
    #pragma unroll
    for (int oi = 0; oi < 4; oi++){
      int o = o0 + w*4 + oi;
      float p = 0.f;
      if (lane < WP){
        int pos = R*WP + lane;
        float yv = y[(((size_t)b*On + o)*HP + i)*WP + lane];
        float r = __expf(yv - mbuf[pos]) * invdbuf[pos];
        p = r*r;
      }
      plds[w*4 + oi][lane] = p;
    }
    __syncthreads();
    int c = lane;
    int s0 = i % 3, s1 = (i+1) % 3, s2g = (i+2) % 3;
    #pragma unroll 1
    for (int jj0 = 0; jj0 < 56; jj0 += 8){
      float xv[3][12];
      #pragma unroll
      for (int q = 0; q < 12; q++){
        xv[0][q] = planes[s0][jj0+q][c];
        xv[1][q] = planes[s1][jj0+q][c];
        xv[2][q] = planes[s2g][jj0+q][c];
      }
      #pragma unroll
      for (int oi = 0; oi < 4; oi++){
        float4 pa = *(const float4*)&plds[w*4+oi][jj0];
        float4 pbq = *(const float4*)&plds[w*4+oi][jj0+4];
        float pv[8] = {pa.x,pa.y,pa.z,pa.w,pbq.x,pbq.y,pbq.z,pbq.w};
        #pragma unroll
        for (int kh = 0; kh < 3; kh++)
          #pragma unroll
          for (int kw = 0; kw < 3; kw++)
            #pragma unroll
            for (int dj = 0; dj < 8; dj++)
              acc[oi][kh*3+kw] += pv[dj]*xv[kh][dj+kw];
      }
    }
    {
      float xv[3][12];
      #pragma unroll
      for (int q = 0; q < 12; q++){
        bool ok = (56 + q) < 64;
        xv[0][q] = ok ? planes[s0][56+q][c] : 0.f;
        xv[1][q] = ok ? planes[s1][56+q][c] : 0.f;
        xv[2][q] = ok ? planes[s2g][56+q][c] : 0.f;
      }
      #pragma unroll
      for (int oi = 0; oi < 4; oi++){
        float4 pa = *(const float4*)&plds[w*4+oi][56];
        float4 pbq = *(const float4*)&plds[w*4+oi][60];
        float pv[8] = {pa.x,pa.y,pa.z,pa.w,pbq.x,pbq.y,pbq.z,pbq.w};
        #pragma unroll
        for (int kh = 0; kh < 3; kh++)
          #pragma unroll
          for (int kw = 0; kw < 3; kw++)
            #pragma unroll
            for (int dj = 0; dj < 8; dj++)
              acc[oi][kh*3+kw] += pv[dj]*xv[kh][dj+kw];
      }
    }
    __syncthreads();
  }
  #pragma unroll
  for (int oi = 0; oi < 4; oi++){
    float* Gr = G + (size_t)(o0 + w*4 + oi)*CKn + lane*9;
    #pragma unroll
    for (int q = 0; q < 9; q++) atomicAdd(&Gr[q], acc[oi][q]);
  }
}

__global__ __launch_bounds__(576) void k_final_old(const float* __restrict__ w, const float* __restrict__ G,
                                                   const float* __restrict__ S1, const float* __restrict__ S2,
                                                   float* __restrict__ dw){
  int o = blockIdx.x; int k = threadIdx.x;
  float s1 = S1[o]; if (s1 == 0.f) s1 = 1.f;
  dw[o*CKn + k] = (G[o*CKn + k] - S2[o]*w[o*CKn + k]) / s1;
}

extern "C" void kernel_launch(void* const* d_in, const int* in_sizes, int n_in,
                              void* d_out, int out_size, void* d_ws, size_t ws_size,
                              hipStream_t stream){
  const float* x    = (const float*)d_in[0];
  const float* w    = (const float*)d_in[1];
  const float* bias = (const float*)d_in[2];
  float* y  = (float*)d_out;
  float* dw = (float*)d_out + Y_ELEMS;
  float* ws = (float*)d_ws;

  if (ws_size >= WS_NEED){
    float* S1 = ws + NS1;
    float* S2 = ws + NS2;
    float* G  = ws + NG;
    ushort16* wnb = (ushort16*)(ws + NWNB);
    ushort16* xb  = (ushort16*)(ws + NXB);
    ushort16* pb  = (ushort16*)(ws + NPB);
    k_norm  <<<dim3(On),      dim3(256), 0, stream>>>(w, wnb, S1, S2, G, KSB);
    k_xb    <<<dim3(8192),    dim3(256), 0, stream>>>(x, xb);
    k_convm <<<dim3(31, Bn),  dim3(256), 0, stream>>>(x, wnb, bias, y);
    k_softp <<<dim3(Bn, 31),  dim3(256), 0, stream>>>(y, pb, S1, S2);
    k_deltam<<<dim3(32, Bn),  dim3(256), 0, stream>>>(xb, pb, G);
    k_finalm<<<dim3(On),      dim3(CKn), 0, stream>>>(w, G, S1, S2, dw);
  } else {
    float* S1   = ws + 73728;
    float* S2   = ws + 73856;
    float* G    = ws + 73984;
    float* mbuf = ws + 147712;
    float* invd = ws + 270720;
    ushort16* wnb = (ushort16*)(ws + 393728);
    k_norm     <<<dim3(On),      dim3(256), 0, stream>>>(w, wnb, S1, S2, G, 1);
    k_convm    <<<dim3(31, Bn),  dim3(256), 0, stream>>>(x, wnb, bias, y);
    k_soft_old <<<dim3(Bn, 16),  dim3(256), 0, stream>>>(y, mbuf, invd, S1, S2);
    k_delta_old<<<dim3(8, Bn*4), dim3(256), 0, stream>>>(x, y, mbuf, invd, G);
    k_final_old<<<dim3(On),      dim3(CKn), 0, stream>>>(w, G, S1, S2, dw);
  }
}